// Round 10
// baseline (172.347 us; speedup 1.0000x reference)
//
#include <hip/hip_runtime.h>
#include <stdint.h>

#define NROWS 65536
#define DIM   256
#define NC    1024
#define NO    64

#define BN    128          // rows per block (4 pairs x 32 rows)
#define BC    64           // centers per tile
#define NTILE (NC / BC)    // 16

using bf16x8 = __bf16 __attribute__((ext_vector_type(8)));
using f32x4  = float __attribute__((ext_vector_type(4)));
using u16x4  = unsigned short __attribute__((ext_vector_type(4)));
using u32x2  = unsigned int __attribute__((ext_vector_type(2)));

#define MFMA16(a, b, c) __builtin_amdgcn_mfma_f32_16x16x32_bf16((a), (b), (c), 0, 0, 0)

__device__ inline unsigned short bf16_bits(float f) {
    __bf16 h = (__bf16)f;   // RNE
    return __builtin_bit_cast(unsigned short, h);
}

// ---------------- merged prep kernel ----------------
// blocks [0,256): centers f32 -> bf16, CHUNK-MAJOR per 64-row tile:
//   chunk q = kc*64 + crow (kc = 16B k-chunk 0..31, crow = row-in-tile 0..63)
//   byte = t*32768 + q*16.  Main kernel's linear global_load_lds then yields
//   conflict-free lane-linear GEMM1 reads (verified R5-R8).
// Also a2 = 2*alpha, acs = alpha*csq (alpha = 1/(2s^2+eps)); exp arg is
// a2*(S - xsq/2) - acs.
// blocks [256,320): W [64,1024] f32 -> bf16 row-major.
__global__ __launch_bounds__(256) void prep(const float* __restrict__ cent,
                                            const float* __restrict__ sigma,
                                            const float* __restrict__ w,
                                            unsigned short* __restrict__ cbf,
                                            float* __restrict__ a2,
                                            float* __restrict__ acs,
                                            unsigned short* __restrict__ wbf) {
    const int bid = blockIdx.x;
    if (bid < 256) {
        const int wid = threadIdx.x >> 6, lane = threadIdx.x & 63;
        const int c = bid * 4 + wid;
        float4 v = ((const float4*)cent)[(size_t)c * 64 + lane];
        u16x4 o;
        o[0] = bf16_bits(v.x); o[1] = bf16_bits(v.y);
        o[2] = bf16_bits(v.z); o[3] = bf16_bits(v.w);
        const int t = c >> 6, crow = c & 63, kc = lane >> 1;
        *(u16x4*)((char*)cbf + t * 32768 + (kc * 64 + crow) * 16 + (lane & 1) * 8) = o;
        float ss = v.x * v.x + v.y * v.y + v.z * v.z + v.w * v.w;
        #pragma unroll
        for (int off = 32; off; off >>= 1) ss += __shfl_down(ss, off);
        if (lane == 0) {
            float s = sigma[c];
            float al = 1.0f / (2.0f * s * s + 1e-8f);
            a2[c] = 2.0f * al;
            acs[c] = al * ss;
        }
    } else {
        const int o = bid - 256;
        float4 v = ((const float4*)w)[(size_t)o * 256 + threadIdx.x];
        u16x4 u;
        u[0] = bf16_bits(v.x); u[1] = bf16_bits(v.y);
        u[2] = bf16_bits(v.z); u[3] = bf16_bits(v.w);
        *(u16x4*)(wbf + (size_t)o * NC + threadIdx.x * 4) = u;
    }
}

// ---------------- main fused kernel ----------------
// R9: 8-wave blocks (512 thr), c-split wave pairs. Pair p owns rows
// blockIdx*128 + p*32..+32; within the pair, wave half=0 computes GEMM1/exp
// for tile-c 0-31, half=1 for c 32-63, into shared rbf_lds[p]; GEMM2 splits
// by output-column half. Same per-wave intensity and per-CU LDS traffic as
// R3, but 4 waves/SIMD instead of 2 (grid 512 x 8 waves = 16 waves/CU).
__global__ __launch_bounds__(512, 4) void rbf_main(
    const float* __restrict__ x,
    const __bf16* __restrict__ cbf, const float* __restrict__ a2,
    const float* __restrict__ acs, const __bf16* __restrict__ wbf,
    const float* __restrict__ bias, float* __restrict__ out) {

    __shared__ __bf16 cent_lds[BC * DIM];     // 32KB, chunk-major [kc][crow]
    __shared__ __bf16 rbf_lds[4][32 * BC];    // 4KB/pair, chunk-major [cc][n]

    const int tid  = threadIdx.x;
    const int wid  = tid >> 6;           // 0..7
    const int pair = wid >> 1;           // 0..3
    const int half = wid & 1;            // c-half of the tile
    const int lane = tid & 63;
    const int l15  = lane & 15;
    const int hi   = lane >> 4;          // 0..3

    const int rowbase = blockIdx.x * BN + pair * 32;

    // stage tile t: 2048 16B chunks over 512 threads (4 each);
    // linear LDS dest = wave-uniform base + lane*16
    auto stage = [&](int t) {
        const char* src = (const char*)cbf + (size_t)t * 32768 + (size_t)tid * 16;
        char* dstb = (char*)cent_lds + (wid * 64) * 16;
        #pragma unroll
        for (int i = 0; i < 4; ++i) {
            __builtin_amdgcn_global_load_lds(
                (const __attribute__((address_space(1))) uint32_t*)(src + i * 8192),
                (__attribute__((address_space(3))) uint32_t*)(dstb + i * 8192), 16, 0, 0);
        }
    };

    stage(0);   // latency covered by the x-load/convert prologue below

    // ---- x fragments straight from f32 global; xsq in-register ----
    // Both waves of a pair load the same 32 rows (each needs all of them).
    bf16x8 xf[2][8];
    float hxsq[2];                        // xsq/2
    #pragma unroll
    for (int nf = 0; nf < 2; ++nf) {
        const float* xr = x + (size_t)(rowbase + nf * 16 + l15) * DIM;
        float ss = 0.f;
        #pragma unroll
        for (int ks = 0; ks < 8; ++ks) {
            float4 a = *(const float4*)(xr + ks * 32 + hi * 8);
            float4 b = *(const float4*)(xr + ks * 32 + hi * 8 + 4);
            bf16x8 f;
            f[0] = (__bf16)a.x; f[1] = (__bf16)a.y; f[2] = (__bf16)a.z; f[3] = (__bf16)a.w;
            f[4] = (__bf16)b.x; f[5] = (__bf16)b.y; f[6] = (__bf16)b.z; f[7] = (__bf16)b.w;
            xf[nf][ks] = f;
            ss += a.x * a.x + a.y * a.y + a.z * a.z + a.w * a.w;
            ss += b.x * b.x + b.y * b.y + b.z * b.z + b.w * b.w;
        }
        ss += __shfl_xor(ss, 16);
        ss += __shfl_xor(ss, 32);
        hxsq[nf] = 0.5f * ss;
    }

    float bo[2];
    #pragma unroll
    for (int of = 0; of < 2; ++of) bo[of] = bias[(half * 2 + of) * 16 + l15];

    f32x4 oacc[2][2];
    #pragma unroll
    for (int nf = 0; nf < 2; ++nf)
        #pragma unroll
        for (int of = 0; of < 2; ++of) {
            f32x4 z = {0.f, 0.f, 0.f, 0.f};
            oacc[nf][of] = z;
        }

    asm volatile("s_waitcnt vmcnt(0)" ::: "memory");
    __syncthreads();   // tile 0 staged

    char* const rbase = (char*)&rbf_lds[pair][0];

    #pragma unroll 1
    for (int t = 0; t < NTILE; ++t) {
        // ---- GEMM1 (swapped): S^T[32c_half][32n], wave's c-half only ----
        // cf read: chunk (ks*4+hi)*64 + half*32 + c4*16 + l15 -> lane-linear
        f32x4 st[2][2];
        #pragma unroll
        for (int c4 = 0; c4 < 2; ++c4)
            #pragma unroll
            for (int nf = 0; nf < 2; ++nf) {
                f32x4 z = {0.f, 0.f, 0.f, 0.f};
                st[c4][nf] = z;
            }
        #pragma unroll
        for (int ks = 0; ks < 8; ++ks) {
            bf16x8 cf[2];
            #pragma unroll
            for (int c4 = 0; c4 < 2; ++c4)
                cf[c4] = *(const bf16x8*)((const char*)cent_lds
                          + ((ks * 4 + hi) * 64 + half * 32 + c4 * 16 + l15) * 16);
            #pragma unroll
            for (int c4 = 0; c4 < 2; ++c4)
                #pragma unroll
                for (int nf = 0; nf < 2; ++nf)
                    st[c4][nf] = MFMA16(cf[c4], xf[nf][ks], st[c4][nf]);
        }

        // ---- rbf = exp(a2*(S - xsq/2) - acs), pack bf16, stage to pair buf ----
        // c_local = half*32 + c4*16 + hi*4 -> chunk cc = half*4 + c4*2 + hi/2
        #pragma unroll
        for (int c4 = 0; c4 < 2; ++c4) {
            const int cg = t * BC + half * 32 + c4 * 16 + hi * 4;
            const f32x4 a24 = *(const f32x4*)(a2 + cg);
            const f32x4 ac4 = *(const f32x4*)(acs + cg);
            #pragma unroll
            for (int nf = 0; nf < 2; ++nf) {
                const f32x4 v = st[c4][nf];
                float p0 = __expf(a24[0] * (v[0] - hxsq[nf]) - ac4[0]);
                float p1 = __expf(a24[1] * (v[1] - hxsq[nf]) - ac4[1]);
                float p2 = __expf(a24[2] * (v[2] - hxsq[nf]) - ac4[2]);
                float p3 = __expf(a24[3] * (v[3] - hxsq[nf]) - ac4[3]);
                u32x2 wv;
                wv[0] = (unsigned)bf16_bits(p0) | ((unsigned)bf16_bits(p1) << 16);
                wv[1] = (unsigned)bf16_bits(p2) | ((unsigned)bf16_bits(p3) << 16);
                const int byte = ((half * 4 + c4 * 2 + (hi >> 1)) * 32 + nf * 16 + l15) * 16
                                 + (hi & 1) * 8;
                *(u32x2*)(rbase + byte) = wv;
            }
        }

        __syncthreads();               // cent_lds consumed + pair rbf complete
        if (t + 1 < NTILE) stage(t + 1);   // drain hides under GEMM2

        // ---- GEMM2: oacc += rbf[32n][64c] . Wt[64c][of-half] ----
        // touches only rbf_lds (pair-shared) + W (L2) -> safe under staging
        #pragma unroll
        for (int cs = 0; cs < 2; ++cs) {
            bf16x8 pa[2];
            #pragma unroll
            for (int nf = 0; nf < 2; ++nf)
                pa[nf] = *(const bf16x8*)(rbase
                          + ((cs * 4 + hi) * 32 + nf * 16 + l15) * 16);
            #pragma unroll
            for (int of = 0; of < 2; ++of) {
                const bf16x8 wb = *(const bf16x8*)(wbf
                    + (size_t)((half * 2 + of) * 16 + l15) * NC + t * BC + cs * 32 + hi * 8);
                #pragma unroll
                for (int nf = 0; nf < 2; ++nf)
                    oacc[nf][of] = MFMA16(pa[nf], wb, oacc[nf][of]);
            }
        }

        asm volatile("s_waitcnt vmcnt(0)" ::: "memory");
        __syncthreads();               // tile t+1 staged; rbf consumed
    }

    // epilogue: D layout row = hi*4 + r (n), col = l15 (o); wave covers
    // its 32 rows x its 32-col half
    #pragma unroll
    for (int nf = 0; nf < 2; ++nf)
        #pragma unroll
        for (int of = 0; of < 2; ++of)
            #pragma unroll
            for (int r = 0; r < 4; ++r) {
                const int n = rowbase + nf * 16 + hi * 4 + r;
                out[(size_t)n * NO + (half * 2 + of) * 16 + l15] = oacc[nf][of][r] + bo[of];
            }
}

// ---------------- launcher ----------------
extern "C" void kernel_launch(void* const* d_in, const int* in_sizes, int n_in,
                              void* d_out, int out_size, void* d_ws, size_t ws_size,
                              hipStream_t stream) {
    const float* x     = (const float*)d_in[0];
    const float* cent  = (const float*)d_in[1];
    const float* sigma = (const float*)d_in[2];
    const float* W     = (const float*)d_in[3];
    const float* b     = (const float*)d_in[4];
    float* out = (float*)d_out;

    char* ws = (char*)d_ws;
    unsigned short* cbf  = (unsigned short*)(ws + 0);        //   524,288 B
    float*          a2p  = (float*)(ws + 524288);            //     4,096 B
    float*          acsp = (float*)(ws + 528384);            //     4,096 B
    unsigned short* wbf  = (unsigned short*)(ws + 532480);   //   131,072 B

    prep<<<320, 256, 0, stream>>>(cent, sigma, W, cbf, a2p, acsp, wbf);
    rbf_main<<<NROWS / BN, 512, 0, stream>>>(
        x, (const __bf16*)cbf, a2p, acsp, (const __bf16*)wbf, b, out);
}